// Round 1
// baseline (14205.110 us; speedup 1.0000x reference)
//
#include <hip/hip_runtime.h>
#include <math.h>

// ---------------------------------------------------------------------------
// SequencePredictorGRU — fused persistent kernel, fp16 MFMA, fp32 accum.
// Each block owns 128 rows for init_mlp + all 20 GRU steps (rows independent).
// h state: LDS fp16 [128][512], XOR-swizzled (byte ^= (m&7)<<4) so that
// 16-row-strided ds_read_b128 A-fragments are conflict-free.
// Weights pre-converted/transposed to fp16 (K-contiguous rows) in d_ws so
// MFMA B-fragments are direct 16B global loads (L2-resident, ~3.1MB total).
// MFMA layouts (guide-verified, 16x16x32):
//   A: row=l&15, k=(l>>4)*8+i (8 contiguous)   B: k=(l>>4)*8+i, col=l&15
//   C/D: col=l&15, row=(l>>4)*4+r
// ---------------------------------------------------------------------------

typedef _Float16 f16;
typedef _Float16 f16x8 __attribute__((ext_vector_type(8)));
typedef float f32x4 __attribute__((ext_vector_type(4)));

#define TSTEPS 20

__device__ __forceinline__ float sigm(float v) { return 1.0f / (1.0f + __expf(-v)); }
__device__ __forceinline__ float tanh_s(float v) {
  float e = __expf(-2.0f * fabsf(v));
  float r = (1.0f - e) / (1.0f + e);
  return copysignf(r, v);
}
__device__ __forceinline__ float gelu_e(float v) {
  return 0.5f * v * (1.0f + erff(v * 0.70710678118654752f));
}
__device__ __forceinline__ unsigned pk2(float a, float b) {
  unsigned short ua = __builtin_bit_cast(unsigned short, (f16)a);
  unsigned short ub = __builtin_bit_cast(unsigned short, (f16)b);
  return (unsigned)ua | ((unsigned)ub << 16);
}
// h region: 128 rows x 512 f16 (1024B rows), swizzled
__device__ __forceinline__ int haddr(int m, int k) {
  return m * 1024 + ((k * 2) ^ ((m & 7) << 4));
}
// t1 region (aliases h region): 64 rows x 1024 f16 (2048B rows), swizzled
__device__ __forceinline__ int taddr(int m, int c) {
  return m * 2048 + ((c * 2) ^ ((m & 7) << 4));
}

// ---------------------------------------------------------------------------
// Prologue: convert weights to fp16, K-contiguous rows.
//   w1t [1024][160] = W1^T ; w2t [512][1024] = W2^T ; whh [1536][512] = W_hh ;
//   wo1t [256][512] = Wo1^T
// ---------------------------------------------------------------------------
__global__ void cvt_weights(const float* __restrict__ W1, const float* __restrict__ W2,
                            const float* __restrict__ Whh, const float* __restrict__ Wo1,
                            f16* __restrict__ w1t, f16* __restrict__ w2t,
                            f16* __restrict__ whh, f16* __restrict__ wo1t) {
  int i = blockIdx.x * 256 + threadIdx.x;
  if (i < 163840) { int n = i / 160; int k = i - n * 160; w1t[i] = (f16)W1[k * 1024 + n]; return; }
  i -= 163840;
  if (i < 524288) { int n = i >> 10; int k = i & 1023; w2t[i] = (f16)W2[k * 512 + n]; return; }
  i -= 524288;
  if (i < 786432) { whh[i] = (f16)Whh[i]; return; }
  i -= 786432;
  if (i < 131072) { int o = i >> 9; int k = i & 511; wo1t[i] = (f16)Wo1[k * 256 + o]; return; }
}

// ---------------------------------------------------------------------------
// Main fused kernel: 512 threads = 8 waves, 128 rows/block.
// ---------------------------------------------------------------------------
__global__ __launch_bounds__(512, 2) void gru_main(
    const float* __restrict__ zq, const float* __restrict__ fpr,
    const float* __restrict__ b1, const float* __restrict__ g1, const float* __restrict__ be1,
    const float* __restrict__ b2, const float* __restrict__ stok,
    const float* __restrict__ Wih, const float* __restrict__ bih, const float* __restrict__ bhh,
    const float* __restrict__ bo1, const float* __restrict__ go, const float* __restrict__ beo,
    const float* __restrict__ Wo2, const float* __restrict__ bo2,
    const f16* __restrict__ w1t, const f16* __restrict__ w2t,
    const f16* __restrict__ whh, const f16* __restrict__ wo1t,
    float* __restrict__ out) {
  __shared__ __align__(16) unsigned char sm_h[131072];  // h[128][512] f16 / t1[64][1024] f16
  __shared__ float sm_x[128];
  __shared__ float sm_stats[64][2];

  const int tid = threadIdx.x;
  const int w = tid >> 6;
  const int l = tid & 63;
  const int l16 = l & 15;
  const int l4 = l >> 4;
  const int R0 = blockIdx.x * 128;

  if (tid < 128) sm_x[tid] = stok[0];

  // ======================= init_mlp (two 64-row halves) ====================
  unsigned hold[2][4][4][2];  // h0 held in regs until t1 region is free

  #pragma unroll
  for (int hf = 0; hf < 2; ++hf) {
    const int RH = R0 + hf * 64;
    // ---- G0a: t1 = cat(z_q,f_prior) @ W1 + b1 -> sm_h as t1 (fp16) --------
    #pragma unroll 1
    for (int nc = 0; nc < 4; ++nc) {
      const int j0 = w * 128 + nc * 32;
      f32x4 acc[4][2];
      #pragma unroll
      for (int mt = 0; mt < 4; ++mt)
        #pragma unroll
        for (int nt = 0; nt < 2; ++nt) acc[mt][nt] = (f32x4){0.f, 0.f, 0.f, 0.f};
      #pragma unroll
      for (int kf = 0; kf < 5; ++kf) {
        const int k0 = kf * 32 + l4 * 8;
        f16x8 af[4];
        #pragma unroll
        for (int mt = 0; mt < 4; ++mt) {
          const int m = RH + mt * 16 + l16;
          const float* src = (kf < 4) ? (zq + m * 128 + k0) : (fpr + m * 32 + (k0 - 128));
          float4 v0 = *(const float4*)src;
          float4 v1 = *(const float4*)(src + 4);
          f16x8 a;
          a[0] = (f16)v0.x; a[1] = (f16)v0.y; a[2] = (f16)v0.z; a[3] = (f16)v0.w;
          a[4] = (f16)v1.x; a[5] = (f16)v1.y; a[6] = (f16)v1.z; a[7] = (f16)v1.w;
          af[mt] = a;
        }
        f16x8 bf[2];
        #pragma unroll
        for (int nt = 0; nt < 2; ++nt)
          bf[nt] = *(const f16x8*)(w1t + (j0 + nt * 16 + l16) * 160 + kf * 32 + l4 * 8);
        #pragma unroll
        for (int mt = 0; mt < 4; ++mt)
          #pragma unroll
          for (int nt = 0; nt < 2; ++nt)
            acc[mt][nt] = __builtin_amdgcn_mfma_f32_16x16x32_f16(af[mt], bf[nt], acc[mt][nt], 0, 0, 0);
      }
      #pragma unroll
      for (int nt = 0; nt < 2; ++nt) {
        const int c = j0 + nt * 16 + l16;
        const float bb = b1[c];
        #pragma unroll
        for (int mt = 0; mt < 4; ++mt)
          #pragma unroll
          for (int r = 0; r < 4; ++r) {
            const int lm = mt * 16 + l4 * 4 + r;
            *(f16*)(sm_h + taddr(lm, c)) = (f16)(acc[mt][nt][r] + bb);
          }
      }
    }
    __syncthreads();
    // ---- LN stats over 1024 per row ----------------------------------------
    {
      const int m = tid >> 3;
      const int c0 = (tid & 7) * 128;
      float s = 0.f, ss = 0.f;
      #pragma unroll 4
      for (int c = c0; c < c0 + 128; c += 8) {
        f16x8 v = *(const f16x8*)(sm_h + taddr(m, c));
        #pragma unroll
        for (int i = 0; i < 8; ++i) { float f = (float)v[i]; s += f; ss += f * f; }
      }
      s += __shfl_xor(s, 1); ss += __shfl_xor(ss, 1);
      s += __shfl_xor(s, 2); ss += __shfl_xor(ss, 2);
      s += __shfl_xor(s, 4); ss += __shfl_xor(ss, 4);
      if ((tid & 7) == 0) {
        float mean = s * (1.f / 1024.f);
        float var = ss * (1.f / 1024.f) - mean * mean;
        sm_stats[m][0] = mean;
        sm_stats[m][1] = rsqrtf(var + 1e-5f);
      }
    }
    __syncthreads();
    // ---- LN + GELU in place ------------------------------------------------
    {
      const int m = tid >> 3;
      const int c0 = (tid & 7) * 128;
      const float mean = sm_stats[m][0], rstd = sm_stats[m][1];
      #pragma unroll 2
      for (int c = c0; c < c0 + 128; c += 8) {
        f16x8 v = *(const f16x8*)(sm_h + taddr(m, c));
        float4 ga = *(const float4*)(g1 + c);
        float4 gb = *(const float4*)(g1 + c + 4);
        float4 ba = *(const float4*)(be1 + c);
        float4 bb = *(const float4*)(be1 + c + 4);
        float gs[8] = {ga.x, ga.y, ga.z, ga.w, gb.x, gb.y, gb.z, gb.w};
        float bs[8] = {ba.x, ba.y, ba.z, ba.w, bb.x, bb.y, bb.z, bb.w};
        f16x8 o;
        #pragma unroll
        for (int i = 0; i < 8; ++i) {
          float f = ((float)v[i] - mean) * rstd * gs[i] + bs[i];
          o[i] = (f16)gelu_e(f);
        }
        *(f16x8*)(sm_h + taddr(m, c)) = o;
      }
    }
    __syncthreads();
    // ---- G0b: h_half = tanh(t1g @ W2 + b2), hold in regs -------------------
    {
      const int jb = w * 64;
      f32x4 acc[4][4];
      #pragma unroll
      for (int mt = 0; mt < 4; ++mt)
        #pragma unroll
        for (int nt = 0; nt < 4; ++nt) acc[mt][nt] = (f32x4){0.f, 0.f, 0.f, 0.f};
      #pragma unroll 2
      for (int kf = 0; kf < 32; ++kf) {
        const int k0 = kf * 32 + l4 * 8;
        f16x8 af[4];
        #pragma unroll
        for (int mt = 0; mt < 4; ++mt)
          af[mt] = *(const f16x8*)(sm_h + taddr(mt * 16 + l16, k0));
        f16x8 bf[4];
        #pragma unroll
        for (int nt = 0; nt < 4; ++nt)
          bf[nt] = *(const f16x8*)(w2t + (jb + nt * 16 + l16) * 1024 + k0);
        #pragma unroll
        for (int mt = 0; mt < 4; ++mt)
          #pragma unroll
          for (int nt = 0; nt < 4; ++nt)
            acc[mt][nt] = __builtin_amdgcn_mfma_f32_16x16x32_f16(af[mt], bf[nt], acc[mt][nt], 0, 0, 0);
      }
      #pragma unroll
      for (int nt = 0; nt < 4; ++nt) {
        const float bb = b2[jb + nt * 16 + l16];
        #pragma unroll
        for (int mt = 0; mt < 4; ++mt) {
          float h0 = tanh_s(acc[mt][nt][0] + bb);
          float h1 = tanh_s(acc[mt][nt][1] + bb);
          float h2 = tanh_s(acc[mt][nt][2] + bb);
          float h3 = tanh_s(acc[mt][nt][3] + bb);
          hold[hf][mt][nt][0] = pk2(h0, h1);
          hold[hf][mt][nt][1] = pk2(h2, h3);
        }
      }
    }
    __syncthreads();  // all t1 reads done before next half overwrites region
  }
  // ---- commit h (overwrites t1 region) -------------------------------------
  #pragma unroll
  for (int hf = 0; hf < 2; ++hf)
    #pragma unroll
    for (int mt = 0; mt < 4; ++mt)
      #pragma unroll
      for (int nt = 0; nt < 4; ++nt)
        #pragma unroll
        for (int p = 0; p < 2; ++p) {
          const unsigned u = hold[hf][mt][nt][p];
          const int m = hf * 64 + mt * 16 + l4 * 4 + p * 2;
          const int k = w * 64 + nt * 16 + l16;
          *(unsigned short*)(sm_h + haddr(m, k)) = (unsigned short)u;
          *(unsigned short*)(sm_h + haddr(m + 1, k)) = (unsigned short)(u >> 16);
        }
  __syncthreads();

  // ============================ GRU loop ===================================
  #pragma unroll 1
  for (int t = 0; t < TSTEPS; ++t) {
    // ---- G1: gh = h @ W_hh^T, gate-triple columns per wave ----------------
    unsigned hnew[4][8][2];
    #pragma unroll
    for (int jc = 0; jc < 4; ++jc) {
      const int jj = w * 64 + jc * 16 + l16;
      f32x4 acc[8][3];
      #pragma unroll
      for (int mt = 0; mt < 8; ++mt)
        #pragma unroll
        for (int g = 0; g < 3; ++g) acc[mt][g] = (f32x4){0.f, 0.f, 0.f, 0.f};
      #pragma unroll 2
      for (int kf = 0; kf < 16; ++kf) {
        const int k0 = kf * 32 + l4 * 8;
        f16x8 af[8];
        #pragma unroll
        for (int mt = 0; mt < 8; ++mt)
          af[mt] = *(const f16x8*)(sm_h + haddr(mt * 16 + l16, k0));
        f16x8 bf[3];
        #pragma unroll
        for (int g = 0; g < 3; ++g)
          bf[g] = *(const f16x8*)(whh + (g * 512 + jj) * 512 + k0);
        #pragma unroll
        for (int mt = 0; mt < 8; ++mt)
          #pragma unroll
          for (int g = 0; g < 3; ++g)
            acc[mt][g] = __builtin_amdgcn_mfma_f32_16x16x32_f16(af[mt], bf[g], acc[mt][g], 0, 0, 0);
      }
      const float wr = Wih[jj],        bir = bih[jj],         bhr = bhh[jj];
      const float wz = Wih[512 + jj],  biz = bih[512 + jj],   bhz = bhh[512 + jj];
      const float wn = Wih[1024 + jj], bin_ = bih[1024 + jj], bhn = bhh[1024 + jj];
      #pragma unroll
      for (int mt = 0; mt < 8; ++mt) {
        float hv[4];
        #pragma unroll
        for (int r = 0; r < 4; ++r) {
          const int m = mt * 16 + l4 * 4 + r;
          const float xm = sm_x[m];
          const float gr = sigm(xm * wr + bir + acc[mt][0][r] + bhr);
          const float gz = sigm(xm * wz + biz + acc[mt][1][r] + bhz);
          const float gn = tanh_s(xm * wn + bin_ + gr * (acc[mt][2][r] + bhn));
          const float ho = (float)(*(const f16*)(sm_h + haddr(m, jj)));
          hv[r] = (1.f - gz) * gn + gz * ho;
        }
        hnew[jc][mt][0] = pk2(hv[0], hv[1]);
        hnew[jc][mt][1] = pk2(hv[2], hv[3]);
      }
    }
    __syncthreads();  // all h reads done
    #pragma unroll
    for (int jc = 0; jc < 4; ++jc) {
      const int kk = w * 64 + jc * 16 + l16;
      #pragma unroll
      for (int mt = 0; mt < 8; ++mt)
        #pragma unroll
        for (int p = 0; p < 2; ++p) {
          const unsigned u = hnew[jc][mt][p];
          const int m = mt * 16 + l4 * 4 + p * 2;
          *(unsigned short*)(sm_h + haddr(m, kk)) = (unsigned short)u;
          *(unsigned short*)(sm_h + haddr(m + 1, kk)) = (unsigned short)(u >> 16);
        }
    }
    __syncthreads();  // h_new committed
    // ---- G2: y = gelu(LN(h_new @ Wo1 + bo1)) @ Wo2 + bo2 ------------------
    {
      const int rm = w * 16;
      f32x4 acc2[16];
      #pragma unroll
      for (int nt = 0; nt < 16; ++nt) acc2[nt] = (f32x4){0.f, 0.f, 0.f, 0.f};
      #pragma unroll 2
      for (int kf = 0; kf < 16; ++kf) {
        const int k0 = kf * 32 + l4 * 8;
        const f16x8 a = *(const f16x8*)(sm_h + haddr(rm + l16, k0));
        #pragma unroll
        for (int nt = 0; nt < 16; ++nt) {
          const f16x8 b = *(const f16x8*)(wo1t + (nt * 16 + l16) * 512 + k0);
          acc2[nt] = __builtin_amdgcn_mfma_f32_16x16x32_f16(a, b, acc2[nt], 0, 0, 0);
        }
      }
      float bo1v[16], gov[16], beov[16], wo2v[16];
      #pragma unroll
      for (int nt = 0; nt < 16; ++nt) {
        const int c = nt * 16 + l16;
        bo1v[nt] = bo1[c]; gov[nt] = go[c]; beov[nt] = beo[c]; wo2v[nt] = Wo2[c];
      }
      #pragma unroll
      for (int r = 0; r < 4; ++r) {
        float vr[16];
        float s = 0.f, ss = 0.f;
        #pragma unroll
        for (int nt = 0; nt < 16; ++nt) {
          const float v = acc2[nt][r] + bo1v[nt];
          vr[nt] = v; s += v; ss += v * v;
        }
        s += __shfl_xor(s, 1); ss += __shfl_xor(ss, 1);
        s += __shfl_xor(s, 2); ss += __shfl_xor(ss, 2);
        s += __shfl_xor(s, 4); ss += __shfl_xor(ss, 4);
        s += __shfl_xor(s, 8); ss += __shfl_xor(ss, 8);
        const float mean = s * (1.f / 256.f);
        const float rstd = rsqrtf(ss * (1.f / 256.f) - mean * mean + 1e-5f);
        float yp = 0.f;
        #pragma unroll
        for (int nt = 0; nt < 16; ++nt) {
          const float v = (vr[nt] - mean) * rstd * gov[nt] + beov[nt];
          yp += gelu_e(v) * wo2v[nt];
        }
        yp += __shfl_xor(yp, 1);
        yp += __shfl_xor(yp, 2);
        yp += __shfl_xor(yp, 4);
        yp += __shfl_xor(yp, 8);
        if (l16 == 0) {
          const int m = rm + l4 * 4 + r;
          const float y = yp + bo2[0];
          sm_x[m] = y;
          out[(R0 + m) * 20 + t] = y;
        }
      }
    }
    __syncthreads();  // x feedback visible for next step
  }
}

// ---------------------------------------------------------------------------
extern "C" void kernel_launch(void* const* d_in, const int* in_sizes, int n_in,
                              void* d_out, int out_size, void* d_ws, size_t ws_size,
                              hipStream_t stream) {
  const float* zq   = (const float*)d_in[0];
  const float* fpr  = (const float*)d_in[1];
  const float* W1   = (const float*)d_in[2];
  const float* b1   = (const float*)d_in[3];
  const float* g1   = (const float*)d_in[4];
  const float* be1  = (const float*)d_in[5];
  const float* W2   = (const float*)d_in[6];
  const float* b2   = (const float*)d_in[7];
  const float* stok = (const float*)d_in[8];
  const float* Wih  = (const float*)d_in[9];
  const float* Whh  = (const float*)d_in[10];
  const float* bih  = (const float*)d_in[11];
  const float* bhh  = (const float*)d_in[12];
  const float* Wo1  = (const float*)d_in[13];
  const float* bo1  = (const float*)d_in[14];
  const float* go   = (const float*)d_in[15];
  const float* beo  = (const float*)d_in[16];
  const float* Wo2  = (const float*)d_in[17];
  const float* bo2  = (const float*)d_in[18];

  char* ws = (char*)d_ws;
  f16* w1t  = (f16*)(ws + 0);        // 1024*160*2  = 327680
  f16* w2t  = (f16*)(ws + 327680);   // 512*1024*2  = 1048576
  f16* whh  = (f16*)(ws + 1376256);  // 1536*512*2  = 1572864
  f16* wo1t = (f16*)(ws + 2949120);  // 256*512*2   = 262144  (total ~3.1MB)

  cvt_weights<<<6272, 256, 0, stream>>>(W1, W2, Whh, Wo1, w1t, w2t, whh, wo1t);

  const int N = in_sizes[0] / 128;  // 65536
  gru_main<<<N / 128, 512, 0, stream>>>(zq, fpr, b1, g1, be1, b2, stok, Wih, bih, bhh,
                                        bo1, go, beo, Wo2, bo2, w1t, w2t, whh, wo1t,
                                        (float*)d_out);
}

// Round 2
// 5298.971 us; speedup vs baseline: 2.6807x; 2.6807x over previous
//
#include <hip/hip_runtime.h>
#include <math.h>

// ---------------------------------------------------------------------------
// SequencePredictorGRU — fused persistent kernel, fp16 MFMA, fp32 accum.
// R2: 64 rows/block, DOUBLE-BUFFERED h in LDS (no register-held h_new -> no
// spills, which caused R1's 17 GB of scratch HBM traffic). MFMA operands
// swapped (compute W·h^T): D gives each lane 4 contiguous j for fixed row m,
// so h_new commits as ds_write_b64 and A-operand (weights) streams from L2
// as k-contiguous 16B loads.
// Layouts (16x16x32, guide-verified):
//   A: row=l&15, k=(l>>4)*8+i     B: col=l&15, k=(l>>4)*8+i
//   D: col=l&15 (-> m), row=(l>>4)*4+r (-> j, contiguous quad)
// h buffers: 2 x [64][512] f16, byte ^= (m&7)<<4 swizzle (bank-conflict-free
// for both b128 row reads and b64 quad writes).
// ---------------------------------------------------------------------------

typedef _Float16 f16;
typedef _Float16 f16x4 __attribute__((ext_vector_type(4)));
typedef _Float16 f16x8 __attribute__((ext_vector_type(8)));
typedef float f32x4 __attribute__((ext_vector_type(4)));

#define TSTEPS 20

__device__ __forceinline__ float sigm(float v) { return 1.0f / (1.0f + __expf(-v)); }
__device__ __forceinline__ float tanh_s(float v) {
  float e = __expf(-2.0f * fabsf(v));
  float r = (1.0f - e) / (1.0f + e);
  return copysignf(r, v);
}
__device__ __forceinline__ float gelu_e(float v) {
  return 0.5f * v * (1.0f + erff(v * 0.70710678118654752f));
}
__device__ __forceinline__ void st4(float* d, float4 v) {
  d[0] = v.x; d[1] = v.y; d[2] = v.z; d[3] = v.w;
}

// h region: buf (0 or 65536) + [64][512] f16 rows of 1024 B, swizzled
__device__ __forceinline__ int haddr(int buf, int m, int k) {
  return buf + m * 1024 + ((k * 2) ^ ((m & 7) << 4));
}
// t1 region (aliases both h buffers): [64][1024] f16 rows of 2048 B, swizzled
__device__ __forceinline__ int taddr(int m, int c) {
  return m * 2048 + ((c * 2) ^ ((m & 7) << 4));
}

// ---------------------------------------------------------------------------
// Prologue: convert weights to fp16, K-contiguous rows.
//   w1t [1024][160] = W1^T ; w2t [512][1024] = W2^T ; whh [1536][512] = W_hh ;
//   wo1t [256][512] = Wo1^T
// ---------------------------------------------------------------------------
__global__ void cvt_weights(const float* __restrict__ W1, const float* __restrict__ W2,
                            const float* __restrict__ Whh, const float* __restrict__ Wo1,
                            f16* __restrict__ w1t, f16* __restrict__ w2t,
                            f16* __restrict__ whh, f16* __restrict__ wo1t) {
  int i = blockIdx.x * 256 + threadIdx.x;
  if (i < 163840) { int n = i / 160; int k = i - n * 160; w1t[i] = (f16)W1[k * 1024 + n]; return; }
  i -= 163840;
  if (i < 524288) { int n = i >> 10; int k = i & 1023; w2t[i] = (f16)W2[k * 512 + n]; return; }
  i -= 524288;
  if (i < 786432) { whh[i] = (f16)Whh[i]; return; }
  i -= 786432;
  if (i < 131072) { int o = i >> 9; int k = i & 511; wo1t[i] = (f16)Wo1[k * 256 + o]; return; }
}

// ---------------------------------------------------------------------------
// Main fused kernel: 512 threads = 8 waves, 64 rows/block.
// ---------------------------------------------------------------------------
__global__ __launch_bounds__(512) __attribute__((amdgpu_waves_per_eu(2, 2)))
void gru_main(
    const float* __restrict__ zq, const float* __restrict__ fpr,
    const float* __restrict__ b1, const float* __restrict__ g1, const float* __restrict__ be1,
    const float* __restrict__ b2, const float* __restrict__ stok,
    const float* __restrict__ Wih, const float* __restrict__ bih, const float* __restrict__ bhh,
    const float* __restrict__ bo1, const float* __restrict__ go, const float* __restrict__ beo,
    const float* __restrict__ Wo2, const float* __restrict__ bo2,
    const f16* __restrict__ w1t, const f16* __restrict__ w2t,
    const f16* __restrict__ whh, const f16* __restrict__ wo1t,
    float* __restrict__ out) {
  __shared__ __align__(16) unsigned char sm[131072];  // t1[64][1024] / h dbuf 2x[64][512]
  __shared__ float sm_stat[64 * 9 * 2];               // padded stride 9 (bank spread)
  __shared__ float sm_yp[64 * 9];
  __shared__ float sm_x[64];

  const int tid = threadIdx.x;
  const int w = tid >> 6;
  const int lane = tid & 63;
  const int l16 = lane & 15;
  const int l4 = lane >> 4;
  const int R0 = blockIdx.x * 64;

  if (tid < 64) sm_x[tid] = stok[0];

  // ================= G0a: t1 = cat(zq,fpr) @ W1 + b1 ======================
  #pragma unroll 1
  for (int p = 0; p < 4; ++p) {
    f32x4 acc[4][2];
    #pragma unroll
    for (int mt = 0; mt < 4; ++mt)
      #pragma unroll
      for (int jh = 0; jh < 2; ++jh) acc[mt][jh] = (f32x4){0.f, 0.f, 0.f, 0.f};
    #pragma unroll
    for (int kf = 0; kf < 5; ++kf) {
      const int k0 = kf * 32 + l4 * 8;
      f16x8 B[4];
      #pragma unroll
      for (int mt = 0; mt < 4; ++mt) {
        const int gm = R0 + mt * 16 + l16;
        const float* src = (kf < 4) ? (zq + gm * 128 + k0) : (fpr + gm * 32 + (k0 - 128));
        float4 v0 = *(const float4*)src;
        float4 v1 = *(const float4*)(src + 4);
        f16x8 b;
        b[0] = (f16)v0.x; b[1] = (f16)v0.y; b[2] = (f16)v0.z; b[3] = (f16)v0.w;
        b[4] = (f16)v1.x; b[5] = (f16)v1.y; b[6] = (f16)v1.z; b[7] = (f16)v1.w;
        B[mt] = b;
      }
      f16x8 A[2];
      #pragma unroll
      for (int jh = 0; jh < 2; ++jh)
        A[jh] = *(const f16x8*)(w1t + (w * 128 + (p * 2 + jh) * 16 + l16) * 160 + k0);
      #pragma unroll
      for (int mt = 0; mt < 4; ++mt)
        #pragma unroll
        for (int jh = 0; jh < 2; ++jh)
          acc[mt][jh] = __builtin_amdgcn_mfma_f32_16x16x32_f16(A[jh], B[mt], acc[mt][jh], 0, 0, 0);
    }
    #pragma unroll
    for (int jh = 0; jh < 2; ++jh) {
      const int jq = w * 128 + (p * 2 + jh) * 16 + l4 * 4;
      const float4 bb = *(const float4*)(b1 + jq);
      float bbv[4]; st4(bbv, bb);
      #pragma unroll
      for (int mt = 0; mt < 4; ++mt) {
        const int m = mt * 16 + l16;
        f16x4 v;
        #pragma unroll
        for (int r = 0; r < 4; ++r) v[r] = (f16)(acc[mt][jh][r] + bbv[r]);
        *(f16x4*)(sm + taddr(m, jq)) = v;
      }
    }
  }
  __syncthreads();
  // ================= LN(1024) + GELU in place ==============================
  {
    const int m = lane;  // row = lane, col-block = wave -> conflict-free
    float s = 0.f, ss = 0.f;
    #pragma unroll 4
    for (int cb = 0; cb < 16; ++cb) {
      const int c = w * 128 + cb * 8;
      f16x8 v = *(const f16x8*)(sm + taddr(m, c));
      #pragma unroll
      for (int i = 0; i < 8; ++i) { float f = (float)v[i]; s += f; ss += f * f; }
    }
    sm_stat[(m * 9 + w) * 2] = s;
    sm_stat[(m * 9 + w) * 2 + 1] = ss;
    __syncthreads();
    s = 0.f; ss = 0.f;
    #pragma unroll
    for (int i = 0; i < 8; ++i) { s += sm_stat[(m * 9 + i) * 2]; ss += sm_stat[(m * 9 + i) * 2 + 1]; }
    const float mean = s * (1.f / 1024.f);
    const float rstd = rsqrtf(ss * (1.f / 1024.f) - mean * mean + 1e-5f);
    #pragma unroll 2
    for (int cb = 0; cb < 16; ++cb) {
      const int c = w * 128 + cb * 8;
      f16x8 v = *(const f16x8*)(sm + taddr(m, c));
      float4 ga = *(const float4*)(g1 + c);
      float4 gb = *(const float4*)(g1 + c + 4);
      float4 ba = *(const float4*)(be1 + c);
      float4 bb = *(const float4*)(be1 + c + 4);
      float gs[8] = {ga.x, ga.y, ga.z, ga.w, gb.x, gb.y, gb.z, gb.w};
      float bs[8] = {ba.x, ba.y, ba.z, ba.w, bb.x, bb.y, bb.z, bb.w};
      f16x8 o;
      #pragma unroll
      for (int i = 0; i < 8; ++i)
        o[i] = (f16)gelu_e(((float)v[i] - mean) * rstd * gs[i] + bs[i]);
      *(f16x8*)(sm + taddr(m, c)) = o;
    }
  }
  __syncthreads();
  // ================= G0b: h0 = tanh(t1g @ W2 + b2) ========================
  f16x4 hold[2][4][2];
  #pragma unroll
  for (int p = 0; p < 2; ++p) {
    f32x4 acc[4][2];
    #pragma unroll
    for (int mt = 0; mt < 4; ++mt)
      #pragma unroll
      for (int jh = 0; jh < 2; ++jh) acc[mt][jh] = (f32x4){0.f, 0.f, 0.f, 0.f};
    #pragma unroll 4
    for (int kf = 0; kf < 32; ++kf) {
      const int k0 = kf * 32 + l4 * 8;
      f16x8 B[4];
      #pragma unroll
      for (int mt = 0; mt < 4; ++mt)
        B[mt] = *(const f16x8*)(sm + taddr(mt * 16 + l16, k0));
      f16x8 A[2];
      #pragma unroll
      for (int jh = 0; jh < 2; ++jh)
        A[jh] = *(const f16x8*)(w2t + (w * 64 + (p * 2 + jh) * 16 + l16) * 1024 + k0);
      #pragma unroll
      for (int mt = 0; mt < 4; ++mt)
        #pragma unroll
        for (int jh = 0; jh < 2; ++jh)
          acc[mt][jh] = __builtin_amdgcn_mfma_f32_16x16x32_f16(A[jh], B[mt], acc[mt][jh], 0, 0, 0);
    }
    #pragma unroll
    for (int jh = 0; jh < 2; ++jh) {
      const int jq = w * 64 + (p * 2 + jh) * 16 + l4 * 4;
      const float4 bb = *(const float4*)(b2 + jq);
      float bbv[4]; st4(bbv, bb);
      #pragma unroll
      for (int mt = 0; mt < 4; ++mt) {
        f16x4 v;
        #pragma unroll
        for (int r = 0; r < 4; ++r) v[r] = (f16)tanh_s(acc[mt][jh][r] + bbv[r]);
        hold[p][mt][jh] = v;
      }
    }
  }
  __syncthreads();  // all t1 reads done; safe to overwrite with h
  #pragma unroll
  for (int p = 0; p < 2; ++p)
    #pragma unroll
    for (int jh = 0; jh < 2; ++jh) {
      const int jq = w * 64 + (p * 2 + jh) * 16 + l4 * 4;
      #pragma unroll
      for (int mt = 0; mt < 4; ++mt) {
        const int m = mt * 16 + l16;
        *(f16x4*)(sm + haddr(0, m, jq)) = hold[p][mt][jh];
      }
    }
  __syncthreads();

  // ============================ GRU loop ===================================
  #pragma unroll 1
  for (int t = 0; t < TSTEPS; ++t) {
    const int cur = (t & 1) << 16;
    const int nxt = cur ^ 65536;
    // ---- G1: gates = Whh · h^T (+x·Wih terms), blend -> h[nxt] ----------
    #pragma unroll 1
    for (int p = 0; p < 2; ++p) {
      f32x4 acc[4][3][2];  // [mt][gate][jh]
      #pragma unroll
      for (int mt = 0; mt < 4; ++mt)
        #pragma unroll
        for (int g = 0; g < 3; ++g)
          #pragma unroll
          for (int jh = 0; jh < 2; ++jh) acc[mt][g][jh] = (f32x4){0.f, 0.f, 0.f, 0.f};
      #pragma unroll 4
      for (int kf = 0; kf < 16; ++kf) {
        const int k0 = kf * 32 + l4 * 8;
        f16x8 B[4];
        #pragma unroll
        for (int mt = 0; mt < 4; ++mt)
          B[mt] = *(const f16x8*)(sm + haddr(cur, mt * 16 + l16, k0));
        f16x8 A[3][2];
        #pragma unroll
        for (int g = 0; g < 3; ++g)
          #pragma unroll
          for (int jh = 0; jh < 2; ++jh)
            A[g][jh] = *(const f16x8*)(whh + (g * 512 + w * 64 + (p * 2 + jh) * 16 + l16) * 512 + k0);
        #pragma unroll
        for (int mt = 0; mt < 4; ++mt)
          #pragma unroll
          for (int g = 0; g < 3; ++g)
            #pragma unroll
            for (int jh = 0; jh < 2; ++jh)
              acc[mt][g][jh] = __builtin_amdgcn_mfma_f32_16x16x32_f16(A[g][jh], B[mt], acc[mt][g][jh], 0, 0, 0);
      }
      #pragma unroll
      for (int jh = 0; jh < 2; ++jh) {
        const int jq = w * 64 + (p * 2 + jh) * 16 + l4 * 4;
        float wr[4], wz[4], wn[4], br[4], bz[4], bn[4], cr[4], cz[4], cn[4];
        st4(wr, *(const float4*)(Wih + jq));
        st4(wz, *(const float4*)(Wih + 512 + jq));
        st4(wn, *(const float4*)(Wih + 1024 + jq));
        st4(br, *(const float4*)(bih + jq));
        st4(bz, *(const float4*)(bih + 512 + jq));
        st4(bn, *(const float4*)(bih + 1024 + jq));
        st4(cr, *(const float4*)(bhh + jq));
        st4(cz, *(const float4*)(bhh + 512 + jq));
        st4(cn, *(const float4*)(bhh + 1024 + jq));
        #pragma unroll
        for (int mt = 0; mt < 4; ++mt) {
          const int m = mt * 16 + l16;
          const float x = sm_x[m];
          const int hoff = m * 1024 + ((jq * 2) ^ ((m & 7) << 4));
          const f16x4 ho = *(const f16x4*)(sm + cur + hoff);
          f16x4 hn;
          #pragma unroll
          for (int r = 0; r < 4; ++r) {
            const float gr = sigm(x * wr[r] + br[r] + acc[mt][0][jh][r] + cr[r]);
            const float gz = sigm(x * wz[r] + bz[r] + acc[mt][1][jh][r] + cz[r]);
            const float gn = tanh_s(x * wn[r] + bn[r] + gr * (acc[mt][2][jh][r] + cn[r]));
            hn[r] = (f16)((1.f - gz) * gn + gz * (float)ho[r]);
          }
          *(f16x4*)(sm + nxt + hoff) = hn;
        }
      }
    }
    __syncthreads();  // h[nxt] complete
    // ---- G2: y = gelu(LN(h_new @ Wo1 + bo1)) @ Wo2 + bo2 ------------------
    {
      f32x4 a2[4][2];  // [mt][jt]
      #pragma unroll
      for (int mt = 0; mt < 4; ++mt)
        #pragma unroll
        for (int jt = 0; jt < 2; ++jt) a2[mt][jt] = (f32x4){0.f, 0.f, 0.f, 0.f};
      #pragma unroll 4
      for (int kf = 0; kf < 16; ++kf) {
        const int k0 = kf * 32 + l4 * 8;
        f16x8 B[4];
        #pragma unroll
        for (int mt = 0; mt < 4; ++mt)
          B[mt] = *(const f16x8*)(sm + haddr(nxt, mt * 16 + l16, k0));
        f16x8 A[2];
        #pragma unroll
        for (int jt = 0; jt < 2; ++jt)
          A[jt] = *(const f16x8*)(wo1t + (w * 32 + jt * 16 + l16) * 512 + k0);
        #pragma unroll
        for (int mt = 0; mt < 4; ++mt)
          #pragma unroll
          for (int jt = 0; jt < 2; ++jt)
            a2[mt][jt] = __builtin_amdgcn_mfma_f32_16x16x32_f16(A[jt], B[mt], a2[mt][jt], 0, 0, 0);
      }
      float vv[4][2][4];
      float bo1v[2][4];
      #pragma unroll
      for (int jt = 0; jt < 2; ++jt)
        st4(bo1v[jt], *(const float4*)(bo1 + w * 32 + jt * 16 + l4 * 4));
      float sA[4], sB[4];
      #pragma unroll
      for (int mt = 0; mt < 4; ++mt) {
        float s = 0.f, ss = 0.f;
        #pragma unroll
        for (int jt = 0; jt < 2; ++jt)
          #pragma unroll
          for (int r = 0; r < 4; ++r) {
            const float v = a2[mt][jt][r] + bo1v[jt][r];
            vv[mt][jt][r] = v; s += v; ss += v * v;
          }
        s += __shfl_xor(s, 16); ss += __shfl_xor(ss, 16);
        s += __shfl_xor(s, 32); ss += __shfl_xor(ss, 32);
        sA[mt] = s; sB[mt] = ss;
      }
      if (l4 == 0) {
        #pragma unroll
        for (int mt = 0; mt < 4; ++mt) {
          const int m = mt * 16 + l16;
          sm_stat[(m * 9 + w) * 2] = sA[mt];
          sm_stat[(m * 9 + w) * 2 + 1] = sB[mt];
        }
      }
      __syncthreads();
      float gov[2][4], bev[2][4], wv[2][4];
      #pragma unroll
      for (int jt = 0; jt < 2; ++jt) {
        const int jb = w * 32 + jt * 16 + l4 * 4;
        st4(gov[jt], *(const float4*)(go + jb));
        st4(bev[jt], *(const float4*)(beo + jb));
        st4(wv[jt], *(const float4*)(Wo2 + jb));
      }
      float yp[4];
      #pragma unroll
      for (int mt = 0; mt < 4; ++mt) {
        const int m = mt * 16 + l16;
        float s = 0.f, ss = 0.f;
        #pragma unroll
        for (int i = 0; i < 8; ++i) {
          s += sm_stat[(m * 9 + i) * 2];
          ss += sm_stat[(m * 9 + i) * 2 + 1];
        }
        const float mean = s * (1.f / 256.f);
        const float rstd = rsqrtf(ss * (1.f / 256.f) - mean * mean + 1e-5f);
        float y = 0.f;
        #pragma unroll
        for (int jt = 0; jt < 2; ++jt)
          #pragma unroll
          for (int r = 0; r < 4; ++r)
            y += gelu_e((vv[mt][jt][r] - mean) * rstd * gov[jt][r] + bev[jt][r]) * wv[jt][r];
        y += __shfl_xor(y, 16);
        y += __shfl_xor(y, 32);
        yp[mt] = y;
      }
      if (l4 == 0) {
        #pragma unroll
        for (int mt = 0; mt < 4; ++mt)
          sm_yp[(mt * 16 + l16) * 9 + w] = yp[mt];
      }
      __syncthreads();
      if (w == 0 && l4 == 0) {
        #pragma unroll
        for (int mt = 0; mt < 4; ++mt) {
          const int m = mt * 16 + l16;
          float y = bo2[0];
          #pragma unroll
          for (int i = 0; i < 8; ++i) y += sm_yp[m * 9 + i];
          sm_x[m] = y;
          out[(R0 + m) * 20 + t] = y;
        }
      }
      __syncthreads();  // x feedback visible for next step
    }
  }
}

// ---------------------------------------------------------------------------
extern "C" void kernel_launch(void* const* d_in, const int* in_sizes, int n_in,
                              void* d_out, int out_size, void* d_ws, size_t ws_size,
                              hipStream_t stream) {
  const float* zq   = (const float*)d_in[0];
  const float* fpr  = (const float*)d_in[1];
  const float* W1   = (const float*)d_in[2];
  const float* b1   = (const float*)d_in[3];
  const float* g1   = (const float*)d_in[4];
  const float* be1  = (const float*)d_in[5];
  const float* W2   = (const float*)d_in[6];
  const float* b2   = (const float*)d_in[7];
  const float* stok = (const float*)d_in[8];
  const float* Wih  = (const float*)d_in[9];
  const float* Whh  = (const float*)d_in[10];
  const float* bih  = (const float*)d_in[11];
  const float* bhh  = (const float*)d_in[12];
  const float* Wo1  = (const float*)d_in[13];
  const float* bo1  = (const float*)d_in[14];
  const float* go   = (const float*)d_in[15];
  const float* beo  = (const float*)d_in[16];
  const float* Wo2  = (const float*)d_in[17];
  const float* bo2  = (const float*)d_in[18];

  char* ws = (char*)d_ws;
  f16* w1t  = (f16*)(ws + 0);        // 1024*160*2  = 327680
  f16* w2t  = (f16*)(ws + 327680);   // 512*1024*2  = 1048576
  f16* whh  = (f16*)(ws + 1376256);  // 1536*512*2  = 1572864
  f16* wo1t = (f16*)(ws + 2949120);  // 256*512*2   = 262144  (total ~3.1MB)

  cvt_weights<<<6272, 256, 0, stream>>>(W1, W2, Whh, Wo1, w1t, w2t, whh, wo1t);

  const int N = in_sizes[0] / 128;  // 65536 rows
  gru_main<<<N / 64, 512, 0, stream>>>(zq, fpr, b1, g1, be1, b2, stok, Wih, bih, bhh,
                                       bo1, go, beo, Wo2, bo2, w1t, w2t, whh, wo1t,
                                       (float*)d_out);
}